// Round 22
// baseline (6467.496 us; speedup 1.0000x reference)
//
#include <hip/hip_runtime.h>
#include <hip/hip_fp16.h>

#define D 64
// Baseline-skeleton SpMM + y-transform + fp16 y (one 128B row per gather).
// Round-21 lesson: fp8 e4m3 FAILS the bf16-floor threshold (7.6e-6 > 3.05e-6,
// exactly the predicted quantization noise) -> fp16 is the byte floor.
// Round-22 change: 3-deep gather pipeline (2 row-gathers in flight per wave,
// 8 groups x 2 = 16 outstanding lines) to test whether ~56 lines/ns is the
// random-line service ceiling or we are still MLP-limited.
// Accumulation/acc/output all stay fp32. No nontemporal ops anywhere.

__global__ void degree_kernel(const int* __restrict__ col, int* __restrict__ deg, int E) {
    int e = blockIdx.x * blockDim.x + threadIdx.x;
    if (e < E) atomicAdd(&deg[col[e]], 1);
}

__global__ void dinv_kernel(const int* __restrict__ deg, float* __restrict__ dinv, int n) {
    int i = blockIdx.x * blockDim.x + threadIdx.x;
    if (i < n) {
        int d = deg[i];
        dinv[i] = (d > 0) ? rsqrtf((float)d) : 0.0f;
    }
}

// Single-workgroup exclusive scan over N elements (runs once per call).
__global__ __launch_bounds__(1024) void scan_kernel(const int* __restrict__ deg,
                                                    int* __restrict__ row_ptr, int n) {
    __shared__ int wsum[16];
    const int tid = threadIdx.x;
    const int lane = tid & 63;
    const int w = tid >> 6;
    int carry = 0;
    for (int base = 0; base < n; base += 1024) {
        int i = base + tid;
        int v = (i < n) ? deg[i] : 0;
        int x = v;
#pragma unroll
        for (int off = 1; off < 64; off <<= 1) {
            int y = __shfl_up(x, off);
            if (lane >= off) x += y;
        }
        if (lane == 63) wsum[w] = x;
        __syncthreads();
        if (w == 0 && lane < 16) {
            int s = wsum[lane];
#pragma unroll
            for (int off = 1; off < 16; off <<= 1) {
                int y = __shfl_up(s, off);
                if (lane >= off) s += y;
            }
            wsum[lane] = s;
        }
        __syncthreads();
        int pref = (w > 0) ? wsum[w - 1] : 0;
        if (i < n) row_ptr[i] = carry + pref + (x - v);
        carry += wsum[15];
        __syncthreads();
    }
    if (tid == 0) row_ptr[n] = carry;
}

// CSR build: only src ids (y-transform removed per-edge weights).
__global__ void scatter_kernel(const int* __restrict__ row, const int* __restrict__ col,
                               const int* __restrict__ row_ptr, int* __restrict__ cursor,
                               int* __restrict__ csr_src, int E) {
    int e = blockIdx.x * blockDim.x + threadIdx.x;
    if (e < E) {
        int s = row[e];
        int d = col[e];
        int pos = row_ptr[d] + atomicAdd(&cursor[d], 1);
        csr_src[pos] = s;
    }
}

// acc0 = emb (fp32, in d_out); y0 = half(dinv * emb), [node][64] half layout.
__global__ void init_kernel(const float4* __restrict__ emb, const float* __restrict__ dinv,
                            __half* __restrict__ y, float4* __restrict__ outAcc, int n) {
    int i = blockIdx.x * blockDim.x + threadIdx.x;   // over n*16 float4s
    if (i < n * 16) {
        int node = i >> 4;
        int t = i & 15;
        float dv = dinv[node];
        float4 v = emb[i];
        outAcc[i] = v;
        __half2 h0 = __float22half2_rn(make_float2(v.x * dv, v.y * dv));
        __half2 h1 = __float22half2_rn(make_float2(v.z * dv, v.w * dv));
        int2 wbits;
        wbits.x = __builtin_bit_cast(int, h0);
        wbits.y = __builtin_bit_cast(int, h1);
        *(int2*)(y + (size_t)node * D + t * 4) = wbits;
    }
}

// One wave per dst node. 8 edge-groups of 8 lanes; lane t of a group loads the
// 16B int4 of dims [8t,8t+8) -> one group gather = one 128B row. 3-deep
// pipeline: TWO gathers in flight (r0 consumed, r1 issued last iter, r2 issued
// this iter); indices prefetched 3 iterations ahead. Wave-uniform loop bounds;
// tails via mask-FMAs (idx 0 is a hot line).
__global__ __launch_bounds__(256) void spmm_kernel(
    const __half* __restrict__ y_in, __half* __restrict__ y_out,
    float4* __restrict__ acc, const int* __restrict__ row_ptr,
    const int* __restrict__ csr_src, const float* __restrict__ dinv, int n) {
    int wv = (int)((blockIdx.x * blockDim.x + threadIdx.x) >> 6);
    int lane = threadIdx.x & 63;
    if (wv >= n) return;
    int g = lane >> 3;   // edge subgroup 0..7
    int t = lane & 7;    // int4 slot within the 128B row
    int beg = row_ptr[wv], end = row_ptr[wv + 1];
    float s0 = 0.f, s1 = 0.f, s2 = 0.f, s3 = 0.f;
    float s4 = 0.f, s5 = 0.f, s6 = 0.f, s7 = 0.f;

    // pipeline prologue: 3 indices, 2 gathers in flight
    int e0 = beg + g;
    int i0 = 0; float m0 = 0.f;
    if (e0 < end) { i0 = csr_src[e0]; m0 = 1.f; }
    int e1 = e0 + 8;
    int i1 = 0; float m1 = 0.f;
    if (e1 < end) { i1 = csr_src[e1]; m1 = 1.f; }
    int e2 = e0 + 16;
    int i2 = 0; float m2 = 0.f;
    if (e2 < end) { i2 = csr_src[e2]; m2 = 1.f; }
    int4 r0 = *(const int4*)(y_in + (size_t)i0 * D + t * 8);
    int4 r1 = *(const int4*)(y_in + (size_t)i1 * D + t * 8);

    for (int e = beg; e < end; e += 8) {
        // issue the 3rd gather (masked-dummy near the tail)
        int4 r2 = *(const int4*)(y_in + (size_t)i2 * D + t * 8);
        // prefetch index three iterations ahead
        int e3 = e + 24 + g;
        int i3 = 0; float m3 = 0.f;
        if (e3 < end) { i3 = csr_src[e3]; m3 = 1.f; }
        // consume current gather
        float2 f0 = __half22float2(__builtin_bit_cast(__half2, r0.x));
        float2 f1 = __half22float2(__builtin_bit_cast(__half2, r0.y));
        float2 f2 = __half22float2(__builtin_bit_cast(__half2, r0.z));
        float2 f3 = __half22float2(__builtin_bit_cast(__half2, r0.w));
        s0 = fmaf(m0, f0.x, s0); s1 = fmaf(m0, f0.y, s1);
        s2 = fmaf(m0, f1.x, s2); s3 = fmaf(m0, f1.y, s3);
        s4 = fmaf(m0, f2.x, s4); s5 = fmaf(m0, f2.y, s5);
        s6 = fmaf(m0, f3.x, s6); s7 = fmaf(m0, f3.y, s7);
        // rotate pipeline
        r0 = r1; r1 = r2;
        m0 = m1; m1 = m2; m2 = m3;
        i2 = i3;
    }

    // reduce the 8 edge-groups (lanes differing in bits 3,4,5)
#pragma unroll
    for (int off = 8; off < 64; off <<= 1) {
        s0 += __shfl_xor(s0, off); s1 += __shfl_xor(s1, off);
        s2 += __shfl_xor(s2, off); s3 += __shfl_xor(s3, off);
        s4 += __shfl_xor(s4, off); s5 += __shfl_xor(s5, off);
        s6 += __shfl_xor(s6, off); s7 += __shfl_xor(s7, off);
    }

    if (g == 0) {
        const float dv = dinv[wv];
        float x0 = dv * s0, x1 = dv * s1, x2 = dv * s2, x3 = dv * s3;  // x_{l+1}
        float x4 = dv * s4, x5 = dv * s5, x6 = dv * s6, x7 = dv * s7;
        const int o = wv * 16 + t * 2;   // dims [8t, 8t+8) = float4s 2t, 2t+1
        float4 a = acc[o];
        a.x += x0; a.y += x1; a.z += x2; a.w += x3;
        acc[o] = a;
        float4 b = acc[o + 1];
        b.x += x4; b.y += x5; b.z += x6; b.w += x7;
        acc[o + 1] = b;
        __half2 h0 = __float22half2_rn(make_float2(dv * x0, dv * x1));  // y_{l+1}
        __half2 h1 = __float22half2_rn(make_float2(dv * x2, dv * x3));
        __half2 h2 = __float22half2_rn(make_float2(dv * x4, dv * x5));
        __half2 h3 = __float22half2_rn(make_float2(dv * x6, dv * x7));
        int4 wbits;
        wbits.x = __builtin_bit_cast(int, h0);
        wbits.y = __builtin_bit_cast(int, h1);
        wbits.z = __builtin_bit_cast(int, h2);
        wbits.w = __builtin_bit_cast(int, h3);
        *(int4*)(y_out + (size_t)wv * D + t * 8) = wbits;
    }
}

__global__ void scale_kernel(float4* __restrict__ out, float f, int n4) {
    int i = blockIdx.x * blockDim.x + threadIdx.x;
    if (i < n4) {
        float4 a = out[i];
        a.x *= f; a.y *= f; a.z *= f; a.w *= f;
        out[i] = a;
    }
}

extern "C" void kernel_launch(void* const* d_in, const int* in_sizes, int n_in,
                              void* d_out, int out_size, void* d_ws, size_t ws_size,
                              hipStream_t stream) {
    const float* emb = (const float*)d_in[0];
    const int* eidx = (const int*)d_in[1];
    const int N = in_sizes[0] / D;   // 90000
    const int E = in_sizes[1] / 2;   // 3000000
    const int L = 100;
    const int* row = eidx;       // edge_index[0]
    const int* col = eidx + E;   // edge_index[1]

    size_t off = 0;
    auto alloc = [&](size_t bytes) -> void* {
        void* p = (char*)d_ws + off;
        off += (bytes + 255) & ~(size_t)255;
        return p;
    };
    int*    deg     = (int*)alloc((size_t)N * 4);
    float*  dinv    = (float*)alloc((size_t)N * 4);
    int*    row_ptr = (int*)alloc((size_t)(N + 1) * 4);
    int*    cursor  = (int*)alloc((size_t)N * 4);
    int*    csr_src = (int*)alloc((size_t)E * 4);
    __half* yA      = (__half*)alloc((size_t)N * D * 2);
    __half* yB      = (__half*)alloc((size_t)N * D * 2);

    (void)hipMemsetAsync(deg, 0, (size_t)N * 4, stream);
    (void)hipMemsetAsync(cursor, 0, (size_t)N * 4, stream);

    degree_kernel<<<(E + 255) / 256, 256, 0, stream>>>(col, deg, E);
    dinv_kernel<<<(N + 255) / 256, 256, 0, stream>>>(deg, dinv, N);
    scan_kernel<<<1, 1024, 0, stream>>>(deg, row_ptr, N);
    scatter_kernel<<<(E + 255) / 256, 256, 0, stream>>>(row, col, row_ptr, cursor,
                                                        csr_src, E);

    float* out = (float*)d_out;
    init_kernel<<<(N * 16 + 255) / 256, 256, 0, stream>>>((const float4*)emb, dinv,
                                                          yA, (float4*)out, N);

    const __half* yin = yA;
    __half* yout = yB;
    for (int l = 0; l < L; ++l) {
        spmm_kernel<<<(N + 3) / 4, 256, 0, stream>>>(yin, yout, (float4*)out,
                                                     row_ptr, csr_src, dinv, N);
        const __half* tmp = yin;
        yin = yout;
        yout = (__half*)tmp;
    }

    const int n4 = N * D / 4;
    scale_kernel<<<(n4 + 255) / 256, 256, 0, stream>>>((float4*)out, 1.0f / (float)(L + 1), n4);
}